// Round 5
// baseline (339.627 us; speedup 1.0000x reference)
//
#include <hip/hip_runtime.h>
#include <stdint.h>

#define DEVINL __device__ __forceinline__

typedef float  f32x4  __attribute__((ext_vector_type(4)));
typedef float  f32x16 __attribute__((ext_vector_type(16)));
typedef short  s16x8  __attribute__((ext_vector_type(8)));
typedef unsigned short u16x8 __attribute__((ext_vector_type(8)));

static constexpr int Bb = 2, S = 2048, D = 1024, H = 16, DK = 64;
static constexpr size_t OUT0 = (size_t)Bb * S * D;   // 4194304

DEVINL unsigned short f2bf(float f) {
  union { float f; unsigned u; } v; v.f = f;
  unsigned r = v.u + 0x7FFFu + ((v.u >> 16) & 1u);   // RNE
  return (unsigned short)(r >> 16);
}

DEVINL unsigned cvt_pk_bf16(float lo, float hi) {
  unsigned r;
  asm("v_cvt_pk_bf16_f32 %0, %1, %2" : "=v"(r) : "v"(lo), "v"(hi));
  return r;
}

DEVINL void perm32swap(unsigned& a, unsigned& b) {
#if __has_builtin(__builtin_amdgcn_permlane32_swap)
  auto r = __builtin_amdgcn_permlane32_swap(a, b, false, false);
  a = r[0]; b = r[1];
#else
  asm volatile("v_permlane32_swap_b32 %0, %1" : "+v"(a), "+v"(b));
#endif
}

DEVINL void gload_lds16(const void* g, void* l) {
  __builtin_amdgcn_global_load_lds(
      (const __attribute__((address_space(1))) unsigned int*)g,
      (__attribute__((address_space(3))) unsigned int*)l, 16, 0, 0);
}

// ---------------- fp32 -> bf16 converts (fused launches) ----------------
DEVINL void cvt_body(const float* __restrict__ src, unsigned short* __restrict__ dst, int i) {
  const f32x4* s4 = (const f32x4*)src;
  f32x4 a = s4[i * 2], b = s4[i * 2 + 1];
  u16x8 o;
  o[0] = f2bf(a[0]); o[1] = f2bf(a[1]); o[2] = f2bf(a[2]); o[3] = f2bf(a[3]);
  o[4] = f2bf(b[0]); o[5] = f2bf(b[1]); o[6] = f2bf(b[2]); o[7] = f2bf(b[3]);
  ((u16x8*)dst)[i] = o;
}

__global__ __launch_bounds__(256) void k_cvt3(const float* __restrict__ a, const float* __restrict__ b,
                                              const float* __restrict__ c,
                                              unsigned short* __restrict__ oa, unsigned short* __restrict__ ob,
                                              unsigned short* __restrict__ oc) {
  int z = blockIdx.y;
  const float* src = z == 0 ? a : z == 1 ? b : c;
  unsigned short* dst = z == 0 ? oa : z == 1 ? ob : oc;
  cvt_body(src, dst, blockIdx.x * 256 + threadIdx.x);
}

__global__ __launch_bounds__(256) void k_cvt4(const float* __restrict__ a, const float* __restrict__ b,
                                              const float* __restrict__ c, const float* __restrict__ d,
                                              unsigned short* __restrict__ oa, unsigned short* __restrict__ ob,
                                              unsigned short* __restrict__ oc, unsigned short* __restrict__ od) {
  int z = blockIdx.y;
  const float* src = z == 0 ? a : z == 1 ? b : z == 2 ? c : d;
  unsigned short* dst = z == 0 ? oa : z == 1 ? ob : z == 2 ? oc : od;
  cvt_body(src, dst, blockIdx.x * 256 + threadIdx.x);
}

// ---------------- GEMM core: C[128,128] tile of A[M,1024] @ W[N,1024]^T ----
template <int MODE>
DEVINL void gemm_tile(const unsigned short* __restrict__ A,
                      const unsigned short* __restrict__ Bw,
                      const float* __restrict__ bias, void* __restrict__ Cout,
                      int tileM, int tileN, float scl,
                      unsigned short* As, unsigned short* Bs) {
  const int tid = threadIdx.x;
  const int lane = tid & 63, wave = tid >> 6;
  const int wr = wave >> 1, wc = wave & 1;
  const int l15 = lane & 15, l16 = lane >> 4;
  f32x4 acc[4][4] = {};
  for (int k0 = 0; k0 < 1024; k0 += 32) {
#pragma unroll
    for (int p = 0; p < 2; ++p) {
      int c = tid + p * 256;
      int row = c >> 2, col = (c & 3) * 8;
      gload_lds16(A + (((size_t)(tileM + row)) << 10) + k0 + col, &As[c * 8]);
      gload_lds16(Bw + (((size_t)(tileN + row)) << 10) + k0 + col, &Bs[c * 8]);
    }
    __syncthreads();
    s16x8 af[4], bf[4];
#pragma unroll
    for (int i = 0; i < 4; ++i)
      af[i] = *(const s16x8*)&As[(wr * 64 + i * 16 + l15) * 32 + l16 * 8];
#pragma unroll
    for (int i = 0; i < 4; ++i)
      bf[i] = *(const s16x8*)&Bs[(wc * 64 + i * 16 + l15) * 32 + l16 * 8];
#pragma unroll
    for (int i = 0; i < 4; ++i)
#pragma unroll
      for (int j = 0; j < 4; ++j)
        acc[i][j] = __builtin_amdgcn_mfma_f32_16x16x32_bf16(af[i], bf[j], acc[i][j], 0, 0, 0);
    __syncthreads();
  }
#pragma unroll
  for (int i = 0; i < 4; ++i) {
#pragma unroll
    for (int j = 0; j < 4; ++j) {
      int n = tileN + wc * 64 + j * 16 + l15;
      float bv = bias[n];
#pragma unroll
      for (int r = 0; r < 4; ++r) {
        int m = tileM + wr * 64 + i * 16 + l16 * 4 + r;
        float v = (acc[i][j][r] + bv) * scl;
        if (MODE == 0) {
          int b_ = m >> 11, s_ = m & 2047, h_ = n >> 6, d_ = n & 63;
          ((unsigned short*)Cout)[(((size_t)(b_ * H + h_) * S) + s_) * DK + d_] = f2bf(v);
        } else {
          ((float*)Cout)[(size_t)m * 1024 + n] = v;
        }
      }
    }
  }
}

__global__ __launch_bounds__(256) void k_gemm_qkv(
    const unsigned short* __restrict__ Xq, const unsigned short* __restrict__ Xk,
    const unsigned short* __restrict__ Xv,
    const unsigned short* __restrict__ Wq, const unsigned short* __restrict__ Wk,
    const unsigned short* __restrict__ Wv,
    const float* __restrict__ bq, const float* __restrict__ bk, const float* __restrict__ bv,
    unsigned short* __restrict__ oq, unsigned short* __restrict__ ok, unsigned short* __restrict__ ov) {
  __shared__ alignas(16) unsigned short As[128 * 32];
  __shared__ alignas(16) unsigned short Bs[128 * 32];
  int z = blockIdx.z;
  const unsigned short* A = z == 0 ? Xq : z == 1 ? Xk : Xv;
  const unsigned short* W = z == 0 ? Wq : z == 1 ? Wk : Wv;
  const float* bias = z == 0 ? bq : z == 1 ? bk : bv;
  unsigned short* o = z == 0 ? oq : z == 1 ? ok : ov;
  float scl = z == 0 ? 0.125f : 1.0f;
  gemm_tile<0>(A, W, bias, o, blockIdx.y * 128, blockIdx.x * 128, scl, As, Bs);
}

__global__ __launch_bounds__(256) void k_gemm_out(const unsigned short* __restrict__ A,
                                                  const unsigned short* __restrict__ W,
                                                  const float* __restrict__ bias,
                                                  float* __restrict__ Cout) {
  __shared__ alignas(16) unsigned short As[128 * 32];
  __shared__ alignas(16) unsigned short Bs[128 * 32];
  gemm_tile<1>(A, W, bias, Cout, blockIdx.y * 128, blockIdx.x * 128, 1.0f, As, Bs);
}

// ---------------- V transpose: [bh][s][64] -> [bh][64][s] ----------------
__global__ __launch_bounds__(256) void k_transpose_v(const unsigned short* __restrict__ vstd,
                                                     unsigned short* __restrict__ vt) {
  __shared__ alignas(16) unsigned short T[64][72];
  int bh = blockIdx.y, st = blockIdx.x;
  int t = threadIdx.x;
  int rr = t >> 3, cc = (t & 7) * 8;
#pragma unroll
  for (int i = 0; i < 2; ++i) {
    int r = rr + i * 32;
    u16x8 v = *(const u16x8*)&vstd[((size_t)bh * S + st * 64 + r) * 64 + cc];
    *(u16x8*)&T[r][cc] = v;
  }
  __syncthreads();
#pragma unroll
  for (int i = 0; i < 2; ++i) {
    int d = rr + i * 32;
    u16x8 o;
#pragma unroll
    for (int j = 0; j < 8; ++j) o[j] = T[cc + j][d];
    *(u16x8*)&vt[((size_t)bh * 64 + d) * S + st * 64 + cc] = o;
  }
}

// ---------------- attention O-pass: swapped-operand, barrier-free ----------
// grid (16, 32) = 512 blocks, 4 waves; wave owns a 32-q tile, iterates all keys.
// S^T = mfma(K, Q): lane holds S[key-rows][q=l31]. P assembled in-register via
// cvt_pk + permlane32_swap into PV's B-operand; O^T = mfma(V^T, P).
// No LDS / barriers in the loop; lsum finishes with one shfl_xor(32).
__global__ __launch_bounds__(256) void k_attn2(const unsigned short* __restrict__ qw,
                                               const unsigned short* __restrict__ kw,
                                               const unsigned short* __restrict__ vt,
                                               const int* __restrict__ mask,
                                               unsigned short* __restrict__ aout,
                                               float* __restrict__ l2lws) {
  __shared__ alignas(16) float OT[4][32 * 68];
  const float LOG2E = 1.44269504f;
  int flat = blockIdx.y * 16 + blockIdx.x;
  int swz = (flat & 7) * 64 + (flat >> 3);        // bijective, 4 bh per XCD
  const int bh = swz >> 4, bq = swz & 15;
  const int b = bh >> 4, h = bh & 15;
  const int lane = threadIdx.x & 63, wave = threadIdx.x >> 6;
  const int l31 = lane & 31, hi = lane >> 5;
  const int q0 = (bq * 4 + wave) * 32;

  s16x8 qb[4];
  const unsigned short* qbase = qw + ((size_t)bh * S + q0 + l31) * 64 + hi * 8;
#pragma unroll
  for (int kc = 0; kc < 4; ++kc) qb[kc] = *(const s16x8*)(qbase + kc * 16);

  const unsigned short* kpan  = kw + (size_t)bh * S * 64 + hi * 8;
  const unsigned short* vpan0 = vt + ((size_t)(bh * 64 + l31)) * S + hi * 8;
  const unsigned short* vpan1 = vt + ((size_t)(bh * 64 + 32 + l31)) * S + hi * 8;
  const int* mrow = mask + b * S;

  f32x16 oT0 = {}, oT1 = {};
  float lsum = 0.f;

  for (int it = 0; it < 64; ++it) {
    const int key0 = it * 32;
    const unsigned short* kbase = kpan + (size_t)(key0 + l31) * 64;
    f32x16 sT = {};
#pragma unroll
    for (int kc = 0; kc < 4; ++kc) {
      s16x8 ka = *(const s16x8*)(kbase + kc * 16);
      sT = __builtin_amdgcn_mfma_f32_32x32x16_bf16(ka, qb[kc], sT, 0, 0, 0);
    }
    float e[16];
#pragma unroll
    for (int r = 0; r < 16; ++r) {
      int kk = key0 + (r & 3) + 8 * (r >> 2) + 4 * hi;
      e[r] = mrow[kk] ? exp2f(sT[r] * LOG2E) : 0.f;
      lsum += e[r];
    }
    // pack to bf16 pairs; keys per word: x0:(0,1)+4hi x1:(2,3)+4hi x2:(8,9)+4hi x3:(10,11)+4hi
    unsigned x0 = cvt_pk_bf16(e[0], e[1]),  x1 = cvt_pk_bf16(e[2], e[3]);
    unsigned x2 = cvt_pk_bf16(e[4], e[5]),  x3 = cvt_pk_bf16(e[6], e[7]);
    unsigned x4 = cvt_pk_bf16(e[8], e[9]),  x5 = cvt_pk_bf16(e[10], e[11]);
    unsigned x6 = cvt_pk_bf16(e[12], e[13]), x7 = cvt_pk_bf16(e[14], e[15]);
    perm32swap(x0, x2); perm32swap(x1, x3);   // frag0: keys hi*8+0..7
    perm32swap(x4, x6); perm32swap(x5, x7);   // frag1: keys 16+hi*8+0..7
    union { unsigned u[4]; s16x8 v; } p0u, p1u;
    p0u.u[0] = x0; p0u.u[1] = x1; p0u.u[2] = x2; p0u.u[3] = x3;
    p1u.u[0] = x4; p1u.u[1] = x5; p1u.u[2] = x6; p1u.u[3] = x7;

    s16x8 va00 = *(const s16x8*)(vpan0 + key0);
    s16x8 va01 = *(const s16x8*)(vpan0 + key0 + 16);
    s16x8 va10 = *(const s16x8*)(vpan1 + key0);
    s16x8 va11 = *(const s16x8*)(vpan1 + key0 + 16);
    oT0 = __builtin_amdgcn_mfma_f32_32x32x16_bf16(va00, p0u.v, oT0, 0, 0, 0);
    oT0 = __builtin_amdgcn_mfma_f32_32x32x16_bf16(va01, p1u.v, oT0, 0, 0, 0);
    oT1 = __builtin_amdgcn_mfma_f32_32x32x16_bf16(va10, p0u.v, oT1, 0, 0, 0);
    oT1 = __builtin_amdgcn_mfma_f32_32x32x16_bf16(va11, p1u.v, oT1, 0, 0, 0);
  }

  lsum += __shfl_xor(lsum, 32);
  if (hi == 0) l2lws[(size_t)bh * S + q0 + l31] = __log2f(lsum);
  float inv = 1.f / lsum;

  // O^T -> LDS (per-wave region) -> coalesced bf16 store
  float* W = OT[wave];
#pragma unroll
  for (int g = 0; g < 4; ++g) {
    int d0 = 8 * g + 4 * hi;
    f32x4 c0, c1;
#pragma unroll
    for (int j = 0; j < 4; ++j) { c0[j] = oT0[g * 4 + j] * inv; c1[j] = oT1[g * 4 + j] * inv; }
    *(f32x4*)&W[l31 * 68 + d0]      = c0;
    *(f32x4*)&W[l31 * 68 + 32 + d0] = c1;
  }
  __syncthreads();
  int qr = lane >> 1, dh = (lane & 1) * 32;
  const float* R = &W[qr * 68 + dh];
  unsigned short* arow = aout + ((size_t)b * S + q0 + qr) * D + h * 64 + dh;
#pragma unroll
  for (int c = 0; c < 4; ++c) {
    f32x4 a = *(const f32x4*)(R + c * 8);
    f32x4 bb = *(const f32x4*)(R + c * 8 + 4);
    u16x8 o;
#pragma unroll
    for (int j = 0; j < 4; ++j) { o[j] = f2bf(a[j]); o[4 + j] = f2bf(bb[j]); }
    *(u16x8*)(arow + c * 8) = o;
  }
}

// ---------------- attention weights (streaming, barrier-free) ----------------
__global__ __launch_bounds__(256) void k_weights(const unsigned short* __restrict__ qw,
                                                 const unsigned short* __restrict__ kw,
                                                 const int* __restrict__ mask,
                                                 const float* __restrict__ l2lws,
                                                 float* __restrict__ attw) {
  const int bh = blockIdx.y, b = bh >> 4;
  const int q0 = blockIdx.x * 32;
  const int lane = threadIdx.x & 63, wave = threadIdx.x >> 6;
  const int l31 = lane & 31, l32 = lane >> 5;
  const float LOG2E = 1.44269504f;

  s16x8 qa[4];
  const unsigned short* qbase = qw + ((size_t)bh * S + q0 + l31) * 64 + l32 * 8;
#pragma unroll
  for (int kc = 0; kc < 4; ++kc) qa[kc] = *(const s16x8*)(qbase + kc * 16);

  float nl2l[16];
#pragma unroll
  for (int r = 0; r < 16; ++r) {
    int row = (r & 3) + 8 * (r >> 2) + 4 * l32;
    nl2l[r] = l2lws[(size_t)bh * S + q0 + row];
  }

  for (int it = 0; it < 16; ++it) {
    int key0 = it * 128 + wave * 32;
    const unsigned short* kbase = kw + ((size_t)bh * S + key0 + l31) * 64 + l32 * 8;
    s16x8 kb[4];
#pragma unroll
    for (int kc = 0; kc < 4; ++kc) kb[kc] = *(const s16x8*)(kbase + kc * 16);
    f32x16 dacc = {};
#pragma unroll
    for (int kc = 0; kc < 4; ++kc)
      dacc = __builtin_amdgcn_mfma_f32_32x32x16_bf16(qa[kc], kb[kc], dacc, 0, 0, 0);

    int key = key0 + l31;
    int mk = mask[b * S + key];
    float* obase = attw + ((size_t)bh * S + q0) * S + key;
#pragma unroll
    for (int r = 0; r < 16; ++r) {
      int row = (r & 3) + 8 * (r >> 2) + 4 * l32;
      float w = mk ? exp2f(dacc[r] * LOG2E - nl2l[r]) : 0.f;
      __builtin_nontemporal_store(w, obase + (size_t)row * S);
    }
  }
}

// ---------------- host ----------------
extern "C" void kernel_launch(void* const* d_in, const int* in_sizes, int n_in,
                              void* d_out, int out_size, void* d_ws, size_t ws_size,
                              hipStream_t stream) {
  (void)in_sizes; (void)n_in; (void)out_size; (void)ws_size;
  const float* Q  = (const float*)d_in[0];
  const float* K  = (const float*)d_in[1];
  const float* V  = (const float*)d_in[2];
  const int* mask = (const int*)d_in[3];
  const float* Wq = (const float*)d_in[4];
  const float* bq = (const float*)d_in[5];
  const float* Wk = (const float*)d_in[6];
  const float* bk = (const float*)d_in[7];
  const float* Wv = (const float*)d_in[8];
  const float* bv = (const float*)d_in[9];
  const float* Wo = (const float*)d_in[10];
  const float* bo = (const float*)d_in[11];

  char* ws = (char*)d_ws;
  unsigned short* Xbf  = (unsigned short*)(ws + 0);           // [3][4194304] bf16
  unsigned short* Wbf  = (unsigned short*)(ws + 25165824);    // [4][1048576] bf16
  unsigned short* qws  = (unsigned short*)(ws + 33554432);    // [bh][s][64]
  unsigned short* kws  = (unsigned short*)(ws + 41943040);    // [bh][s][64]
  unsigned short* vstd = (unsigned short*)(ws + 50331648);    // [bh][s][64]
  float*          l2l  = (float*)(ws + 58720256);             // [32][2048] fp32
  unsigned short* vt   = (unsigned short*)(ws + 0);           // reuse Xbf[Q] (consumed)
  unsigned short* aoutb= (unsigned short*)(ws + 8388608);     // reuse Xbf[K] (consumed)
  float* out0 = (float*)d_out;
  float* attw = (float*)d_out + OUT0;

  k_cvt3<<<dim3(2048, 3), dim3(256), 0, stream>>>(Q, K, V, Xbf, Xbf + 4194304, Xbf + 8388608);
  k_cvt4<<<dim3(512, 4), dim3(256), 0, stream>>>(Wq, Wk, Wv, Wo,
                                                 Wbf, Wbf + 1048576, Wbf + 2097152, Wbf + 3145728);

  k_gemm_qkv<<<dim3(8, 32, 3), dim3(256), 0, stream>>>(
      Xbf, Xbf + 4194304, Xbf + 8388608,
      Wbf, Wbf + 1048576, Wbf + 2097152,
      bq, bk, bv, qws, kws, vstd);

  k_transpose_v<<<dim3(32, 32), dim3(256), 0, stream>>>(vstd, vt);

  k_attn2<<<dim3(16, 32), dim3(256), 0, stream>>>(qws, kws, vt, mask, aoutb, l2l);

  k_weights<<<dim3(64, 32), dim3(256), 0, stream>>>(qws, kws, mask, l2l, attw);

  k_gemm_out<<<dim3(8, 32), dim3(256), 0, stream>>>(aoutb, Wbf + 3145728, bo, out0);
}

// Round 6
// 290.925 us; speedup vs baseline: 1.1674x; 1.1674x over previous
//
#include <hip/hip_runtime.h>
#include <stdint.h>

#define DEVINL __device__ __forceinline__

typedef float  f32x4  __attribute__((ext_vector_type(4)));
typedef float  f32x16 __attribute__((ext_vector_type(16)));
typedef short  s16x8  __attribute__((ext_vector_type(8)));
typedef unsigned short u16x8 __attribute__((ext_vector_type(8)));

static constexpr int Bb = 2, S = 2048, D = 1024, H = 16, DK = 64;
static constexpr size_t OUT0 = (size_t)Bb * S * D;   // 4194304

DEVINL unsigned short f2bf(float f) {
  union { float f; unsigned u; } v; v.f = f;
  unsigned r = v.u + 0x7FFFu + ((v.u >> 16) & 1u);   // RNE
  return (unsigned short)(r >> 16);
}

DEVINL void gload_lds16(const void* g, void* l) {
  __builtin_amdgcn_global_load_lds(
      (const __attribute__((address_space(1))) unsigned int*)g,
      (__attribute__((address_space(3))) unsigned int*)l, 16, 0, 0);
}

// ---------------- fp32 -> bf16 converts (fused launches) ----------------
DEVINL void cvt_body(const float* __restrict__ src, unsigned short* __restrict__ dst, int i) {
  const f32x4* s4 = (const f32x4*)src;
  f32x4 a = s4[i * 2], b = s4[i * 2 + 1];
  u16x8 o;
  o[0] = f2bf(a[0]); o[1] = f2bf(a[1]); o[2] = f2bf(a[2]); o[3] = f2bf(a[3]);
  o[4] = f2bf(b[0]); o[5] = f2bf(b[1]); o[6] = f2bf(b[2]); o[7] = f2bf(b[3]);
  ((u16x8*)dst)[i] = o;
}

__global__ __launch_bounds__(256) void k_cvt3(const float* __restrict__ a, const float* __restrict__ b,
                                              const float* __restrict__ c,
                                              unsigned short* __restrict__ oa, unsigned short* __restrict__ ob,
                                              unsigned short* __restrict__ oc) {
  int z = blockIdx.y;
  const float* src = z == 0 ? a : z == 1 ? b : c;
  unsigned short* dst = z == 0 ? oa : z == 1 ? ob : oc;
  cvt_body(src, dst, blockIdx.x * 256 + threadIdx.x);
}

__global__ __launch_bounds__(256) void k_cvt4(const float* __restrict__ a, const float* __restrict__ b,
                                              const float* __restrict__ c, const float* __restrict__ d,
                                              unsigned short* __restrict__ oa, unsigned short* __restrict__ ob,
                                              unsigned short* __restrict__ oc, unsigned short* __restrict__ od) {
  int z = blockIdx.y;
  const float* src = z == 0 ? a : z == 1 ? b : z == 2 ? c : d;
  unsigned short* dst = z == 0 ? oa : z == 1 ? ob : z == 2 ? oc : od;
  cvt_body(src, dst, blockIdx.x * 256 + threadIdx.x);
}

// ---------------- GEMM core: C[128,128] tile of A[M,1024] @ W[N,1024]^T ----
template <int MODE>
DEVINL void gemm_tile(const unsigned short* __restrict__ A,
                      const unsigned short* __restrict__ Bw,
                      const float* __restrict__ bias, void* __restrict__ Cout,
                      int tileM, int tileN, float scl,
                      unsigned short* As, unsigned short* Bs) {
  const int tid = threadIdx.x;
  const int lane = tid & 63, wave = tid >> 6;
  const int wr = wave >> 1, wc = wave & 1;
  const int l15 = lane & 15, l16 = lane >> 4;
  f32x4 acc[4][4] = {};
  for (int k0 = 0; k0 < 1024; k0 += 32) {
#pragma unroll
    for (int p = 0; p < 2; ++p) {
      int c = tid + p * 256;
      int row = c >> 2, col = (c & 3) * 8;
      gload_lds16(A + (((size_t)(tileM + row)) << 10) + k0 + col, &As[c * 8]);
      gload_lds16(Bw + (((size_t)(tileN + row)) << 10) + k0 + col, &Bs[c * 8]);
    }
    __syncthreads();
    s16x8 af[4], bf[4];
#pragma unroll
    for (int i = 0; i < 4; ++i)
      af[i] = *(const s16x8*)&As[(wr * 64 + i * 16 + l15) * 32 + l16 * 8];
#pragma unroll
    for (int i = 0; i < 4; ++i)
      bf[i] = *(const s16x8*)&Bs[(wc * 64 + i * 16 + l15) * 32 + l16 * 8];
#pragma unroll
    for (int i = 0; i < 4; ++i)
#pragma unroll
      for (int j = 0; j < 4; ++j)
        acc[i][j] = __builtin_amdgcn_mfma_f32_16x16x32_bf16(af[i], bf[j], acc[i][j], 0, 0, 0);
    __syncthreads();
  }
#pragma unroll
  for (int i = 0; i < 4; ++i) {
#pragma unroll
    for (int j = 0; j < 4; ++j) {
      int n = tileN + wc * 64 + j * 16 + l15;
      float bv = bias[n];
#pragma unroll
      for (int r = 0; r < 4; ++r) {
        int m = tileM + wr * 64 + i * 16 + l16 * 4 + r;
        float v = (acc[i][j][r] + bv) * scl;
        if (MODE == 0) {
          int b_ = m >> 11, s_ = m & 2047, h_ = n >> 6, d_ = n & 63;
          ((unsigned short*)Cout)[(((size_t)(b_ * H + h_) * S) + s_) * DK + d_] = f2bf(v);
        } else {
          ((float*)Cout)[(size_t)m * 1024 + n] = v;
        }
      }
    }
  }
}

__global__ __launch_bounds__(256) void k_gemm_qkv(
    const unsigned short* __restrict__ Xq, const unsigned short* __restrict__ Xk,
    const unsigned short* __restrict__ Xv,
    const unsigned short* __restrict__ Wq, const unsigned short* __restrict__ Wk,
    const unsigned short* __restrict__ Wv,
    const float* __restrict__ bq, const float* __restrict__ bk, const float* __restrict__ bv,
    unsigned short* __restrict__ oq, unsigned short* __restrict__ ok, unsigned short* __restrict__ ov) {
  __shared__ alignas(16) unsigned short As[128 * 32];
  __shared__ alignas(16) unsigned short Bs[128 * 32];
  int z = blockIdx.z;
  const unsigned short* A = z == 0 ? Xq : z == 1 ? Xk : Xv;
  const unsigned short* W = z == 0 ? Wq : z == 1 ? Wk : Wv;
  const float* bias = z == 0 ? bq : z == 1 ? bk : bv;
  unsigned short* o = z == 0 ? oq : z == 1 ? ok : ov;
  float scl = z == 0 ? 0.125f : 1.0f;
  gemm_tile<0>(A, W, bias, o, blockIdx.y * 128, blockIdx.x * 128, scl, As, Bs);
}

__global__ __launch_bounds__(256) void k_gemm_out(const unsigned short* __restrict__ A,
                                                  const unsigned short* __restrict__ W,
                                                  const float* __restrict__ bias,
                                                  float* __restrict__ Cout) {
  __shared__ alignas(16) unsigned short As[128 * 32];
  __shared__ alignas(16) unsigned short Bs[128 * 32];
  gemm_tile<1>(A, W, bias, Cout, blockIdx.y * 128, blockIdx.x * 128, 1.0f, As, Bs);
}

// ------- V transpose: [bh][s][64] -> tile-blocked vt2[bh][kt][64 d][64 s] -------
__global__ __launch_bounds__(256) void k_transpose_v(const unsigned short* __restrict__ vstd,
                                                     unsigned short* __restrict__ vt2) {
  __shared__ alignas(16) unsigned short T[64][72];
  int bh = blockIdx.y, st = blockIdx.x;
  int t = threadIdx.x;
  int rr = t >> 3, cc = (t & 7) * 8;
#pragma unroll
  for (int i = 0; i < 2; ++i) {
    int r = rr + i * 32;
    u16x8 v = *(const u16x8*)&vstd[((size_t)bh * S + st * 64 + r) * 64 + cc];
    *(u16x8*)&T[r][cc] = v;
  }
  __syncthreads();
#pragma unroll
  for (int i = 0; i < 2; ++i) {
    int d = rr + i * 32;
    u16x8 o;
#pragma unroll
    for (int j = 0; j < 8; ++j) o[j] = T[cc + j][d];
    *(u16x8*)&vt2[(size_t)bh * S * 64 + st * 4096 + d * 64 + cc] = o;
  }
}

// ---------------- fused attention phase A: double-buffered, 1 barrier/step ----
// grid (32,32) XCD-swizzled; 4 waves x 16 q-rows; KVBLK=64 per step, 32 steps.
// Per step: STAGE(next) issued FIRST (overlaps compute), QK 16x16x32 MFMA from
// swizzled Ks, exp, shuffle row-sum, P via wave-private LDS, PV from swizzled Vs,
// single __syncthreads (vmcnt0 drain) at end.
__global__ __launch_bounds__(256) void k_attn(const unsigned short* __restrict__ qw,
                                              const unsigned short* __restrict__ kw,
                                              const unsigned short* __restrict__ vt2,
                                              const int* __restrict__ mask,
                                              unsigned short* __restrict__ aout,
                                              float* __restrict__ l2lws) {
  __shared__ alignas(16) unsigned short Ks[2][64 * 64];   // [key][dk] 128B rows
  __shared__ alignas(16) unsigned short Vs[2][64 * 64];   // [d][key]  128B rows
  __shared__ alignas(16) unsigned short Ps[4][16 * 64];   // per-wave [q][key] 128B rows

  int flat = blockIdx.y * 32 + blockIdx.x;                // 1024 blocks
  int swz = (flat & 7) * 128 + (flat >> 3);               // bijective XCD chunks
  const int bh = swz >> 5, qt = swz & 31;
  const int b = bh >> 4, h = bh & 15;
  const int q0 = qt * 64;
  const int tid = threadIdx.x;
  const int lane = tid & 63, wave = tid >> 6;
  const int l15 = lane & 15, l16 = lane >> 4;

  const unsigned short* kw_bh = kw + (size_t)bh * S * 64;
  const unsigned short* vt_bh = vt2 + (size_t)bh * S * 64;
  const int* mrow = mask + b * S;

  const int qrow = q0 + wave * 16 + l15;
  s16x8 qf0 = *(const s16x8*)&qw[((size_t)bh * S + qrow) * 64 + l16 * 8];
  s16x8 qf1 = *(const s16x8*)&qw[((size_t)bh * S + qrow) * 64 + 32 + l16 * 8];

  // prologue stage
  {
#pragma unroll
    for (int p = 0; p < 2; ++p) {
      int c = tid + p * 256, row = c >> 3, cc = (c & 7) ^ (row & 7);
      gload_lds16(kw_bh + (size_t)row * 64 + cc * 8, &Ks[0][c * 8]);
    }
#pragma unroll
    for (int p = 0; p < 2; ++p) {
      int c = tid + p * 256, row = c >> 3, cc = (c & 7) ^ (row & 7);
      gload_lds16(vt_bh + (size_t)row * 64 + cc * 8, &Vs[0][c * 8]);
    }
  }
  __syncthreads();

  f32x4 oacc[4] = {};
  float lsum[4] = {0.f, 0.f, 0.f, 0.f};
  int cur = 0;

  for (int kt = 0; kt < 32; ++kt) {
    if (kt + 1 < 32) {   // prefetch next tile into buf^1 (overlaps compute below)
      int nk = kt + 1;
#pragma unroll
      for (int p = 0; p < 2; ++p) {
        int c = tid + p * 256, row = c >> 3, cc = (c & 7) ^ (row & 7);
        gload_lds16(kw_bh + ((size_t)(nk * 64 + row)) * 64 + cc * 8, &Ks[cur ^ 1][c * 8]);
      }
#pragma unroll
      for (int p = 0; p < 2; ++p) {
        int c = tid + p * 256, row = c >> 3, cc = (c & 7) ^ (row & 7);
        gload_lds16(vt_bh + (size_t)nk * 4096 + row * 64 + cc * 8, &Vs[cur ^ 1][c * 8]);
      }
    }

    const unsigned short* K_ = Ks[cur];
    const unsigned short* V_ = Vs[cur];

    // QK^T: 4 key-blocks x 2 dk-chunks
    f32x4 sac[4] = {};
#pragma unroll
    for (int nb = 0; nb < 4; ++nb) {
#pragma unroll
      for (int dc = 0; dc < 2; ++dc) {
        int row = nb * 16 + l15;
        int off = l16 * 16 + dc * 64;
        s16x8 kf = *(const s16x8*)((const char*)K_ + row * 128 + (off ^ ((row & 7) << 4)));
        sac[nb] = __builtin_amdgcn_mfma_f32_16x16x32_bf16(dc ? qf1 : qf0, kf, sac[nb], 0, 0, 0);
      }
    }

    float e[4][4];
#pragma unroll
    for (int nb = 0; nb < 4; ++nb) {
      int mk = mrow[kt * 64 + nb * 16 + l15];
#pragma unroll
      for (int r = 0; r < 4; ++r) e[nb][r] = mk ? __expf(sac[nb][r]) : 0.f;
    }
#pragma unroll
    for (int r = 0; r < 4; ++r) {
      float t = (e[0][r] + e[1][r]) + (e[2][r] + e[3][r]);
      t += __shfl_xor(t, 1); t += __shfl_xor(t, 2);
      t += __shfl_xor(t, 4); t += __shfl_xor(t, 8);
      lsum[r] += t;
    }

    // P to wave-private LDS (compiler handles the lgkmcnt for the read-back)
    unsigned short* P = Ps[wave];
#pragma unroll
    for (int nb = 0; nb < 4; ++nb)
#pragma unroll
      for (int r = 0; r < 4; ++r) {
        int row = l16 * 4 + r, col = nb * 16 + l15;
        *(unsigned short*)((char*)P + row * 128 + ((col * 2) ^ ((row & 7) << 4))) = f2bf(e[nb][r]);
      }

    s16x8 pf[2];
#pragma unroll
    for (int kc = 0; kc < 2; ++kc)
      pf[kc] = *(const s16x8*)((const char*)P + l15 * 128 + ((kc * 64 + l16 * 16) ^ ((l15 & 7) << 4)));
#pragma unroll
    for (int db = 0; db < 4; ++db) {
      int row = db * 16 + l15;
#pragma unroll
      for (int kc = 0; kc < 2; ++kc) {
        s16x8 vf = *(const s16x8*)((const char*)V_ + row * 128 + ((kc * 64 + l16 * 16) ^ ((row & 7) << 4)));
        oacc[db] = __builtin_amdgcn_mfma_f32_16x16x32_bf16(pf[kc], vf, oacc[db], 0, 0, 0);
      }
    }

    __syncthreads();   // drains vmcnt (prefetch ready) + all waves done with buf[cur]
    cur ^= 1;
  }

  float invl[4];
#pragma unroll
  for (int r = 0; r < 4; ++r) invl[r] = 1.f / lsum[r];

  if (l15 == 0) {
#pragma unroll
    for (int r = 0; r < 4; ++r)
      l2lws[(size_t)bh * S + q0 + wave * 16 + l16 * 4 + r] = log2f(lsum[r]);
  }

#pragma unroll
  for (int db = 0; db < 4; ++db)
#pragma unroll
    for (int r = 0; r < 4; ++r) {
      int m = q0 + wave * 16 + l16 * 4 + r;
      int d = db * 16 + l15;
      aout[((size_t)b * S + m) * D + h * 64 + d] = f2bf(oacc[db][r] * invl[r]);
    }
}

// ---------------- attention weights (streaming, barrier-free) ----------------
__global__ __launch_bounds__(256) void k_weights(const unsigned short* __restrict__ qw,
                                                 const unsigned short* __restrict__ kw,
                                                 const int* __restrict__ mask,
                                                 const float* __restrict__ l2lws,
                                                 float* __restrict__ attw) {
  int flat = blockIdx.y * 64 + blockIdx.x;                // 2048 blocks
  int swz = (flat & 7) * 256 + (flat >> 3);               // bijective XCD chunks
  const int bh = swz >> 6, b = bh >> 4;
  const int q0 = (swz & 63) * 32;
  const int lane = threadIdx.x & 63, wave = threadIdx.x >> 6;
  const int l31 = lane & 31, l32 = lane >> 5;
  const float LOG2E = 1.44269504f;

  s16x8 qa[4];
  const unsigned short* qbase = qw + ((size_t)bh * S + q0 + l31) * 64 + l32 * 8;
#pragma unroll
  for (int kc = 0; kc < 4; ++kc) qa[kc] = *(const s16x8*)(qbase + kc * 16);

  float nl2l[16];
#pragma unroll
  for (int r = 0; r < 16; ++r) {
    int row = (r & 3) + 8 * (r >> 2) + 4 * l32;
    nl2l[r] = l2lws[(size_t)bh * S + q0 + row];
  }

  for (int it = 0; it < 16; ++it) {
    int key0 = it * 128 + wave * 32;
    const unsigned short* kbase = kw + ((size_t)bh * S + key0 + l31) * 64 + l32 * 8;
    s16x8 kb[4];
#pragma unroll
    for (int kc = 0; kc < 4; ++kc) kb[kc] = *(const s16x8*)(kbase + kc * 16);
    f32x16 dacc = {};
#pragma unroll
    for (int kc = 0; kc < 4; ++kc)
      dacc = __builtin_amdgcn_mfma_f32_32x32x16_bf16(qa[kc], kb[kc], dacc, 0, 0, 0);

    int key = key0 + l31;
    int mk = mask[b * S + key];
    float* obase = attw + ((size_t)bh * S + q0) * S + key;
#pragma unroll
    for (int r = 0; r < 16; ++r) {
      int row = (r & 3) + 8 * (r >> 2) + 4 * l32;
      float w = mk ? exp2f(dacc[r] * LOG2E - nl2l[r]) : 0.f;
      __builtin_nontemporal_store(w, obase + (size_t)row * S);
    }
  }
}

// ---------------- host ----------------
extern "C" void kernel_launch(void* const* d_in, const int* in_sizes, int n_in,
                              void* d_out, int out_size, void* d_ws, size_t ws_size,
                              hipStream_t stream) {
  (void)in_sizes; (void)n_in; (void)out_size; (void)ws_size;
  const float* Q  = (const float*)d_in[0];
  const float* K  = (const float*)d_in[1];
  const float* V  = (const float*)d_in[2];
  const int* mask = (const int*)d_in[3];
  const float* Wq = (const float*)d_in[4];
  const float* bq = (const float*)d_in[5];
  const float* Wk = (const float*)d_in[6];
  const float* bk = (const float*)d_in[7];
  const float* Wv = (const float*)d_in[8];
  const float* bv = (const float*)d_in[9];
  const float* Wo = (const float*)d_in[10];
  const float* bo = (const float*)d_in[11];

  char* ws = (char*)d_ws;
  unsigned short* Xbf  = (unsigned short*)(ws + 0);           // [3][4194304] bf16
  unsigned short* Wbf  = (unsigned short*)(ws + 25165824);    // [4][1048576] bf16
  unsigned short* qws  = (unsigned short*)(ws + 33554432);    // [bh][s][64]
  unsigned short* kws  = (unsigned short*)(ws + 41943040);    // [bh][s][64]
  unsigned short* vstd = (unsigned short*)(ws + 50331648);    // [bh][s][64]
  float*          l2l  = (float*)(ws + 58720256);             // [32][2048] fp32
  unsigned short* vt2  = (unsigned short*)(ws + 0);           // reuse Xbf[Q] (consumed)
  unsigned short* aoutb= (unsigned short*)(ws + 8388608);     // reuse Xbf[K] (consumed)
  float* out0 = (float*)d_out;
  float* attw = (float*)d_out + OUT0;

  k_cvt3<<<dim3(2048, 3), dim3(256), 0, stream>>>(Q, K, V, Xbf, Xbf + 4194304, Xbf + 8388608);
  k_cvt4<<<dim3(512, 4), dim3(256), 0, stream>>>(Wq, Wk, Wv, Wo,
                                                 Wbf, Wbf + 1048576, Wbf + 2097152, Wbf + 3145728);

  k_gemm_qkv<<<dim3(8, 32, 3), dim3(256), 0, stream>>>(
      Xbf, Xbf + 4194304, Xbf + 8388608,
      Wbf, Wbf + 1048576, Wbf + 2097152,
      bq, bk, bv, qws, kws, vstd);

  k_transpose_v<<<dim3(32, 32), dim3(256), 0, stream>>>(vstd, vt2);

  k_attn<<<dim3(32, 32), dim3(256), 0, stream>>>(qws, kws, vt2, mask, aoutb, l2l);

  k_weights<<<dim3(64, 32), dim3(256), 0, stream>>>(qws, kws, mask, l2l, attw);

  k_gemm_out<<<dim3(8, 32), dim3(256), 0, stream>>>(aoutb, Wbf + 3145728, bo, out0);
}

// Round 7
// 286.061 us; speedup vs baseline: 1.1873x; 1.0170x over previous
//
#include <hip/hip_runtime.h>
#include <stdint.h>

#define DEVINL __device__ __forceinline__

typedef float  f32x4  __attribute__((ext_vector_type(4)));
typedef float  f32x16 __attribute__((ext_vector_type(16)));
typedef short  s16x8  __attribute__((ext_vector_type(8)));
typedef unsigned short u16x8 __attribute__((ext_vector_type(8)));

static constexpr int Bb = 2, S = 2048, D = 1024, H = 16, DK = 64;
static constexpr size_t OUT0 = (size_t)Bb * S * D;   // 4194304

DEVINL unsigned short f2bf(float f) {
  union { float f; unsigned u; } v; v.f = f;
  unsigned r = v.u + 0x7FFFu + ((v.u >> 16) & 1u);   // RNE
  return (unsigned short)(r >> 16);
}

DEVINL void gload_lds16(const void* g, void* l) {
  __builtin_amdgcn_global_load_lds(
      (const __attribute__((address_space(1))) unsigned int*)g,
      (__attribute__((address_space(3))) unsigned int*)l, 16, 0, 0);
}

// ---------------- fp32 -> bf16 converts (fused launches) ----------------
DEVINL void cvt_body(const float* __restrict__ src, unsigned short* __restrict__ dst, int i) {
  const f32x4* s4 = (const f32x4*)src;
  f32x4 a = s4[i * 2], b = s4[i * 2 + 1];
  u16x8 o;
  o[0] = f2bf(a[0]); o[1] = f2bf(a[1]); o[2] = f2bf(a[2]); o[3] = f2bf(a[3]);
  o[4] = f2bf(b[0]); o[5] = f2bf(b[1]); o[6] = f2bf(b[2]); o[7] = f2bf(b[3]);
  ((u16x8*)dst)[i] = o;
}

__global__ __launch_bounds__(256) void k_cvt3(const float* __restrict__ a, const float* __restrict__ b,
                                              const float* __restrict__ c,
                                              unsigned short* __restrict__ oa, unsigned short* __restrict__ ob,
                                              unsigned short* __restrict__ oc) {
  int z = blockIdx.y;
  const float* src = z == 0 ? a : z == 1 ? b : c;
  unsigned short* dst = z == 0 ? oa : z == 1 ? ob : oc;
  cvt_body(src, dst, blockIdx.x * 256 + threadIdx.x);
}

__global__ __launch_bounds__(256) void k_cvt4(const float* __restrict__ a, const float* __restrict__ b,
                                              const float* __restrict__ c, const float* __restrict__ d,
                                              unsigned short* __restrict__ oa, unsigned short* __restrict__ ob,
                                              unsigned short* __restrict__ oc, unsigned short* __restrict__ od) {
  int z = blockIdx.y;
  const float* src = z == 0 ? a : z == 1 ? b : z == 2 ? c : d;
  unsigned short* dst = z == 0 ? oa : z == 1 ? ob : z == 2 ? oc : od;
  cvt_body(src, dst, blockIdx.x * 256 + threadIdx.x);
}

// ---------------- GEMM core: C[128,128] tile of A[M,1024] @ W[N,1024]^T ----
template <int MODE>
DEVINL void gemm_tile(const unsigned short* __restrict__ A,
                      const unsigned short* __restrict__ Bw,
                      const float* __restrict__ bias, void* __restrict__ Cout,
                      int tileM, int tileN, float scl,
                      unsigned short* As, unsigned short* Bs) {
  const int tid = threadIdx.x;
  const int lane = tid & 63, wave = tid >> 6;
  const int wr = wave >> 1, wc = wave & 1;
  const int l15 = lane & 15, l16 = lane >> 4;
  f32x4 acc[4][4] = {};
  for (int k0 = 0; k0 < 1024; k0 += 32) {
#pragma unroll
    for (int p = 0; p < 2; ++p) {
      int c = tid + p * 256;
      int row = c >> 2, col = (c & 3) * 8;
      gload_lds16(A + (((size_t)(tileM + row)) << 10) + k0 + col, &As[c * 8]);
      gload_lds16(Bw + (((size_t)(tileN + row)) << 10) + k0 + col, &Bs[c * 8]);
    }
    __syncthreads();
    s16x8 af[4], bf[4];
#pragma unroll
    for (int i = 0; i < 4; ++i)
      af[i] = *(const s16x8*)&As[(wr * 64 + i * 16 + l15) * 32 + l16 * 8];
#pragma unroll
    for (int i = 0; i < 4; ++i)
      bf[i] = *(const s16x8*)&Bs[(wc * 64 + i * 16 + l15) * 32 + l16 * 8];
#pragma unroll
    for (int i = 0; i < 4; ++i)
#pragma unroll
      for (int j = 0; j < 4; ++j)
        acc[i][j] = __builtin_amdgcn_mfma_f32_16x16x32_bf16(af[i], bf[j], acc[i][j], 0, 0, 0);
    __syncthreads();
  }
#pragma unroll
  for (int i = 0; i < 4; ++i) {
#pragma unroll
    for (int j = 0; j < 4; ++j) {
      int n = tileN + wc * 64 + j * 16 + l15;
      float bv = bias[n];
#pragma unroll
      for (int r = 0; r < 4; ++r) {
        int m = tileM + wr * 64 + i * 16 + l16 * 4 + r;
        float v = (acc[i][j][r] + bv) * scl;
        if (MODE == 0) {
          int b_ = m >> 11, s_ = m & 2047, h_ = n >> 6, d_ = n & 63;
          ((unsigned short*)Cout)[(((size_t)(b_ * H + h_) * S) + s_) * DK + d_] = f2bf(v);
        } else {
          ((float*)Cout)[(size_t)m * 1024 + n] = v;
        }
      }
    }
  }
}

// Fused QKV projection, XCD-swizzled: 768 blocks -> 96-chunk per XCD so each
// XCD's L2 holds one B panel (2MB) + streaming A panels.
__global__ __launch_bounds__(256) void k_gemm_qkv(
    const unsigned short* __restrict__ Xq, const unsigned short* __restrict__ Xk,
    const unsigned short* __restrict__ Xv,
    const unsigned short* __restrict__ Wq, const unsigned short* __restrict__ Wk,
    const unsigned short* __restrict__ Wv,
    const float* __restrict__ bq, const float* __restrict__ bk, const float* __restrict__ bv,
    unsigned short* __restrict__ oq, unsigned short* __restrict__ ok, unsigned short* __restrict__ ov) {
  __shared__ alignas(16) unsigned short As[128 * 32];
  __shared__ alignas(16) unsigned short Bs[128 * 32];
  int flat = (blockIdx.z * 32 + blockIdx.y) * 8 + blockIdx.x;   // [0,768)
  int swz = (flat & 7) * 96 + (flat >> 3);                      // bijective (768 = 8*96)
  int z = swz >> 8;
  int rem = swz & 255;
  int ty = rem >> 3, tx = rem & 7;
  const unsigned short* A = z == 0 ? Xq : z == 1 ? Xk : Xv;
  const unsigned short* W = z == 0 ? Wq : z == 1 ? Wk : Wv;
  const float* bias = z == 0 ? bq : z == 1 ? bk : bv;
  unsigned short* o = z == 0 ? oq : z == 1 ? ok : ov;
  float scl = z == 0 ? 0.125f : 1.0f;
  gemm_tile<0>(A, W, bias, o, ty * 128, tx * 128, scl, As, Bs);
}

// Output projection, XCD-swizzled: 256 blocks -> 32-chunk per XCD.
__global__ __launch_bounds__(256) void k_gemm_out(const unsigned short* __restrict__ A,
                                                  const unsigned short* __restrict__ W,
                                                  const float* __restrict__ bias,
                                                  float* __restrict__ Cout) {
  __shared__ alignas(16) unsigned short As[128 * 32];
  __shared__ alignas(16) unsigned short Bs[128 * 32];
  int flat = blockIdx.y * 8 + blockIdx.x;                        // [0,256)
  int swz = (flat & 7) * 32 + (flat >> 3);                       // bijective (256 = 8*32)
  int ty = swz >> 3, tx = swz & 7;
  gemm_tile<1>(A, W, bias, Cout, ty * 128, tx * 128, 1.0f, As, Bs);
}

// ------- V transpose: [bh][s][64] -> tile-blocked vt2[bh][kt][64 d][64 s] -------
__global__ __launch_bounds__(256) void k_transpose_v(const unsigned short* __restrict__ vstd,
                                                     unsigned short* __restrict__ vt2) {
  __shared__ alignas(16) unsigned short T[64][72];
  int bh = blockIdx.y, st = blockIdx.x;
  int t = threadIdx.x;
  int rr = t >> 3, cc = (t & 7) * 8;
#pragma unroll
  for (int i = 0; i < 2; ++i) {
    int r = rr + i * 32;
    u16x8 v = *(const u16x8*)&vstd[((size_t)bh * S + st * 64 + r) * 64 + cc];
    *(u16x8*)&T[r][cc] = v;
  }
  __syncthreads();
#pragma unroll
  for (int i = 0; i < 2; ++i) {
    int d = rr + i * 32;
    u16x8 o;
#pragma unroll
    for (int j = 0; j < 8; ++j) o[j] = T[cc + j][d];
    *(u16x8*)&vt2[(size_t)bh * S * 64 + st * 4096 + d * 64 + cc] = o;
  }
}

// ---------------- fused attention phase A: double-buffered, 1 barrier/step ----
__global__ __launch_bounds__(256) void k_attn(const unsigned short* __restrict__ qw,
                                              const unsigned short* __restrict__ kw,
                                              const unsigned short* __restrict__ vt2,
                                              const int* __restrict__ mask,
                                              unsigned short* __restrict__ aout,
                                              float* __restrict__ l2lws) {
  __shared__ alignas(16) unsigned short Ks[2][64 * 64];   // [key][dk] 128B rows
  __shared__ alignas(16) unsigned short Vs[2][64 * 64];   // [d][key]  128B rows
  __shared__ alignas(16) unsigned short Ps[4][16 * 64];   // per-wave [q][key] 128B rows

  int flat = blockIdx.y * 32 + blockIdx.x;                // 1024 blocks
  int swz = (flat & 7) * 128 + (flat >> 3);               // bijective XCD chunks
  const int bh = swz >> 5, qt = swz & 31;
  const int b = bh >> 4, h = bh & 15;
  const int q0 = qt * 64;
  const int tid = threadIdx.x;
  const int lane = tid & 63, wave = tid >> 6;
  const int l15 = lane & 15, l16 = lane >> 4;

  const unsigned short* kw_bh = kw + (size_t)bh * S * 64;
  const unsigned short* vt_bh = vt2 + (size_t)bh * S * 64;
  const int* mrow = mask + b * S;

  const int qrow = q0 + wave * 16 + l15;
  s16x8 qf0 = *(const s16x8*)&qw[((size_t)bh * S + qrow) * 64 + l16 * 8];
  s16x8 qf1 = *(const s16x8*)&qw[((size_t)bh * S + qrow) * 64 + 32 + l16 * 8];

  // prologue stage
  {
#pragma unroll
    for (int p = 0; p < 2; ++p) {
      int c = tid + p * 256, row = c >> 3, cc = (c & 7) ^ (row & 7);
      gload_lds16(kw_bh + (size_t)row * 64 + cc * 8, &Ks[0][c * 8]);
    }
#pragma unroll
    for (int p = 0; p < 2; ++p) {
      int c = tid + p * 256, row = c >> 3, cc = (c & 7) ^ (row & 7);
      gload_lds16(vt_bh + (size_t)row * 64 + cc * 8, &Vs[0][c * 8]);
    }
  }
  __syncthreads();

  f32x4 oacc[4] = {};
  float lsum[4] = {0.f, 0.f, 0.f, 0.f};
  int cur = 0;

  for (int kt = 0; kt < 32; ++kt) {
    if (kt + 1 < 32) {   // prefetch next tile into buf^1 (overlaps compute below)
      int nk = kt + 1;
#pragma unroll
      for (int p = 0; p < 2; ++p) {
        int c = tid + p * 256, row = c >> 3, cc = (c & 7) ^ (row & 7);
        gload_lds16(kw_bh + ((size_t)(nk * 64 + row)) * 64 + cc * 8, &Ks[cur ^ 1][c * 8]);
      }
#pragma unroll
      for (int p = 0; p < 2; ++p) {
        int c = tid + p * 256, row = c >> 3, cc = (c & 7) ^ (row & 7);
        gload_lds16(vt_bh + (size_t)nk * 4096 + row * 64 + cc * 8, &Vs[cur ^ 1][c * 8]);
      }
    }

    const unsigned short* K_ = Ks[cur];
    const unsigned short* V_ = Vs[cur];

    // QK^T: 4 key-blocks x 2 dk-chunks
    f32x4 sac[4] = {};
#pragma unroll
    for (int nb = 0; nb < 4; ++nb) {
#pragma unroll
      for (int dc = 0; dc < 2; ++dc) {
        int row = nb * 16 + l15;
        int off = l16 * 16 + dc * 64;
        s16x8 kf = *(const s16x8*)((const char*)K_ + row * 128 + (off ^ ((row & 7) << 4)));
        sac[nb] = __builtin_amdgcn_mfma_f32_16x16x32_bf16(dc ? qf1 : qf0, kf, sac[nb], 0, 0, 0);
      }
    }

    float e[4][4];
#pragma unroll
    for (int nb = 0; nb < 4; ++nb) {
      int mk = mrow[kt * 64 + nb * 16 + l15];
#pragma unroll
      for (int r = 0; r < 4; ++r) e[nb][r] = mk ? __expf(sac[nb][r]) : 0.f;
    }
#pragma unroll
    for (int r = 0; r < 4; ++r) {
      float t = (e[0][r] + e[1][r]) + (e[2][r] + e[3][r]);
      t += __shfl_xor(t, 1); t += __shfl_xor(t, 2);
      t += __shfl_xor(t, 4); t += __shfl_xor(t, 8);
      lsum[r] += t;
    }

    // P to wave-private LDS (compiler handles the lgkmcnt for the read-back)
    unsigned short* P = Ps[wave];
#pragma unroll
    for (int nb = 0; nb < 4; ++nb)
#pragma unroll
      for (int r = 0; r < 4; ++r) {
        int row = l16 * 4 + r, col = nb * 16 + l15;
        *(unsigned short*)((char*)P + row * 128 + ((col * 2) ^ ((row & 7) << 4))) = f2bf(e[nb][r]);
      }

    s16x8 pf[2];
#pragma unroll
    for (int kc = 0; kc < 2; ++kc)
      pf[kc] = *(const s16x8*)((const char*)P + l15 * 128 + ((kc * 64 + l16 * 16) ^ ((l15 & 7) << 4)));
#pragma unroll
    for (int db = 0; db < 4; ++db) {
      int row = db * 16 + l15;
#pragma unroll
      for (int kc = 0; kc < 2; ++kc) {
        s16x8 vf = *(const s16x8*)((const char*)V_ + row * 128 + ((kc * 64 + l16 * 16) ^ ((row & 7) << 4)));
        oacc[db] = __builtin_amdgcn_mfma_f32_16x16x32_bf16(pf[kc], vf, oacc[db], 0, 0, 0);
      }
    }

    __syncthreads();   // drains vmcnt (prefetch ready) + all waves done with buf[cur]
    cur ^= 1;
  }

  float invl[4];
#pragma unroll
  for (int r = 0; r < 4; ++r) invl[r] = 1.f / lsum[r];

  if (l15 == 0) {
#pragma unroll
    for (int r = 0; r < 4; ++r)
      l2lws[(size_t)bh * S + q0 + wave * 16 + l16 * 4 + r] = log2f(lsum[r]);
  }

#pragma unroll
  for (int db = 0; db < 4; ++db)
#pragma unroll
    for (int r = 0; r < 4; ++r) {
      int m = q0 + wave * 16 + l16 * 4 + r;
      int d = db * 16 + l15;
      aout[((size_t)b * S + m) * D + h * 64 + d] = f2bf(oacc[db][r] * invl[r]);
    }
}

// ---------------- attention weights (streaming, barrier-free) ----------------
__global__ __launch_bounds__(256) void k_weights(const unsigned short* __restrict__ qw,
                                                 const unsigned short* __restrict__ kw,
                                                 const int* __restrict__ mask,
                                                 const float* __restrict__ l2lws,
                                                 float* __restrict__ attw) {
  int flat = blockIdx.y * 64 + blockIdx.x;                // 2048 blocks
  int swz = (flat & 7) * 256 + (flat >> 3);               // bijective XCD chunks
  const int bh = swz >> 6, b = bh >> 4;
  const int q0 = (swz & 63) * 32;
  const int lane = threadIdx.x & 63, wave = threadIdx.x >> 6;
  const int l31 = lane & 31, l32 = lane >> 5;
  const float LOG2E = 1.44269504f;

  s16x8 qa[4];
  const unsigned short* qbase = qw + ((size_t)bh * S + q0 + l31) * 64 + l32 * 8;
#pragma unroll
  for (int kc = 0; kc < 4; ++kc) qa[kc] = *(const s16x8*)(qbase + kc * 16);

  float nl2l[16];
#pragma unroll
  for (int r = 0; r < 16; ++r) {
    int row = (r & 3) + 8 * (r >> 2) + 4 * l32;
    nl2l[r] = l2lws[(size_t)bh * S + q0 + row];
  }

  for (int it = 0; it < 16; ++it) {
    int key0 = it * 128 + wave * 32;
    const unsigned short* kbase = kw + ((size_t)bh * S + key0 + l31) * 64 + l32 * 8;
    s16x8 kb[4];
#pragma unroll
    for (int kc = 0; kc < 4; ++kc) kb[kc] = *(const s16x8*)(kbase + kc * 16);
    f32x16 dacc = {};
#pragma unroll
    for (int kc = 0; kc < 4; ++kc)
      dacc = __builtin_amdgcn_mfma_f32_32x32x16_bf16(qa[kc], kb[kc], dacc, 0, 0, 0);

    int key = key0 + l31;
    int mk = mask[b * S + key];
    float* obase = attw + ((size_t)bh * S + q0) * S + key;
#pragma unroll
    for (int r = 0; r < 16; ++r) {
      int row = (r & 3) + 8 * (r >> 2) + 4 * l32;
      float w = mk ? exp2f(dacc[r] * LOG2E - nl2l[r]) : 0.f;
      __builtin_nontemporal_store(w, obase + (size_t)row * S);
    }
  }
}

// ---------------- host ----------------
extern "C" void kernel_launch(void* const* d_in, const int* in_sizes, int n_in,
                              void* d_out, int out_size, void* d_ws, size_t ws_size,
                              hipStream_t stream) {
  (void)in_sizes; (void)n_in; (void)out_size; (void)ws_size;
  const float* Q  = (const float*)d_in[0];
  const float* K  = (const float*)d_in[1];
  const float* V  = (const float*)d_in[2];
  const int* mask = (const int*)d_in[3];
  const float* Wq = (const float*)d_in[4];
  const float* bq = (const float*)d_in[5];
  const float* Wk = (const float*)d_in[6];
  const float* bk = (const float*)d_in[7];
  const float* Wv = (const float*)d_in[8];
  const float* bv = (const float*)d_in[9];
  const float* Wo = (const float*)d_in[10];
  const float* bo = (const float*)d_in[11];

  char* ws = (char*)d_ws;
  unsigned short* Xbf  = (unsigned short*)(ws + 0);           // [3][4194304] bf16
  unsigned short* Wbf  = (unsigned short*)(ws + 25165824);    // [4][1048576] bf16
  unsigned short* qws  = (unsigned short*)(ws + 33554432);    // [bh][s][64]
  unsigned short* kws  = (unsigned short*)(ws + 41943040);    // [bh][s][64]
  unsigned short* vstd = (unsigned short*)(ws + 50331648);    // [bh][s][64]
  float*          l2l  = (float*)(ws + 58720256);             // [32][2048] fp32
  unsigned short* vt2  = (unsigned short*)(ws + 0);           // reuse Xbf[Q] (consumed)
  unsigned short* aoutb= (unsigned short*)(ws + 8388608);     // reuse Xbf[K] (consumed)
  float* out0 = (float*)d_out;
  float* attw = (float*)d_out + OUT0;

  k_cvt3<<<dim3(2048, 3), dim3(256), 0, stream>>>(Q, K, V, Xbf, Xbf + 4194304, Xbf + 8388608);
  k_cvt4<<<dim3(512, 4), dim3(256), 0, stream>>>(Wq, Wk, Wv, Wo,
                                                 Wbf, Wbf + 1048576, Wbf + 2097152, Wbf + 3145728);

  k_gemm_qkv<<<dim3(8, 32, 3), dim3(256), 0, stream>>>(
      Xbf, Xbf + 4194304, Xbf + 8388608,
      Wbf, Wbf + 1048576, Wbf + 2097152,
      bq, bk, bv, qws, kws, vstd);

  k_transpose_v<<<dim3(32, 32), dim3(256), 0, stream>>>(vstd, vt2);

  k_attn<<<dim3(32, 32), dim3(256), 0, stream>>>(qws, kws, vt2, mask, aoutb, l2l);

  k_weights<<<dim3(64, 32), dim3(256), 0, stream>>>(qws, kws, mask, l2l, attw);

  k_gemm_out<<<dim3(8, 32), dim3(256), 0, stream>>>(aoutb, Wbf + 3145728, bo, out0);
}

// Round 8
// 247.496 us; speedup vs baseline: 1.3723x; 1.1558x over previous
//
#include <hip/hip_runtime.h>
#include <stdint.h>

#define DEVINL __device__ __forceinline__

typedef float  f32x4  __attribute__((ext_vector_type(4)));
typedef float  f32x16 __attribute__((ext_vector_type(16)));
typedef short  s16x8  __attribute__((ext_vector_type(8)));
typedef unsigned short u16x8 __attribute__((ext_vector_type(8)));

static constexpr int Bb = 2, S = 2048, D = 1024, H = 16, DK = 64;
static constexpr size_t OUT0 = (size_t)Bb * S * D;   // 4194304

DEVINL unsigned short f2bf(float f) {
  union { float f; unsigned u; } v; v.f = f;
  unsigned r = v.u + 0x7FFFu + ((v.u >> 16) & 1u);   // RNE
  return (unsigned short)(r >> 16);
}

DEVINL unsigned cvt_pk_bf16(float lo, float hi) {
  unsigned r;
  asm("v_cvt_pk_bf16_f32 %0, %1, %2" : "=v"(r) : "v"(lo), "v"(hi));
  return r;
}

DEVINL void perm32swap(unsigned& a, unsigned& b) {
#if __has_builtin(__builtin_amdgcn_permlane32_swap)
  auto r = __builtin_amdgcn_permlane32_swap(a, b, false, false);
  a = r[0]; b = r[1];
#else
  asm volatile("v_permlane32_swap_b32 %0, %1" : "+v"(a), "+v"(b));
#endif
}

DEVINL void gload_lds16(const void* g, void* l) {
  __builtin_amdgcn_global_load_lds(
      (const __attribute__((address_space(1))) unsigned int*)g,
      (__attribute__((address_space(3))) unsigned int*)l, 16, 0, 0);
}

// ---------------- fp32 -> bf16 converts (fused launches) ----------------
DEVINL void cvt_body(const float* __restrict__ src, unsigned short* __restrict__ dst, int i) {
  const f32x4* s4 = (const f32x4*)src;
  f32x4 a = s4[i * 2], b = s4[i * 2 + 1];
  u16x8 o;
  o[0] = f2bf(a[0]); o[1] = f2bf(a[1]); o[2] = f2bf(a[2]); o[3] = f2bf(a[3]);
  o[4] = f2bf(b[0]); o[5] = f2bf(b[1]); o[6] = f2bf(b[2]); o[7] = f2bf(b[3]);
  ((u16x8*)dst)[i] = o;
}

__global__ __launch_bounds__(256) void k_cvt3(const float* __restrict__ a, const float* __restrict__ b,
                                              const float* __restrict__ c,
                                              unsigned short* __restrict__ oa, unsigned short* __restrict__ ob,
                                              unsigned short* __restrict__ oc) {
  int z = blockIdx.y;
  const float* src = z == 0 ? a : z == 1 ? b : c;
  unsigned short* dst = z == 0 ? oa : z == 1 ? ob : oc;
  cvt_body(src, dst, blockIdx.x * 256 + threadIdx.x);
}

__global__ __launch_bounds__(256) void k_cvt4(const float* __restrict__ a, const float* __restrict__ b,
                                              const float* __restrict__ c, const float* __restrict__ d,
                                              unsigned short* __restrict__ oa, unsigned short* __restrict__ ob,
                                              unsigned short* __restrict__ oc, unsigned short* __restrict__ od) {
  int z = blockIdx.y;
  const float* src = z == 0 ? a : z == 1 ? b : z == 2 ? c : d;
  unsigned short* dst = z == 0 ? oa : z == 1 ? ob : z == 2 ? oc : od;
  cvt_body(src, dst, blockIdx.x * 256 + threadIdx.x);
}

// ---------------- GEMM core: C[128,128] tile of A[M,1024] @ W[N,1024]^T ----
template <int MODE>
DEVINL void gemm_tile(const unsigned short* __restrict__ A,
                      const unsigned short* __restrict__ Bw,
                      const float* __restrict__ bias, void* __restrict__ Cout,
                      int tileM, int tileN, float scl,
                      unsigned short* As, unsigned short* Bs) {
  const int tid = threadIdx.x;
  const int lane = tid & 63, wave = tid >> 6;
  const int wr = wave >> 1, wc = wave & 1;
  const int l15 = lane & 15, l16 = lane >> 4;
  f32x4 acc[4][4] = {};
  for (int k0 = 0; k0 < 1024; k0 += 32) {
#pragma unroll
    for (int p = 0; p < 2; ++p) {
      int c = tid + p * 256;
      int row = c >> 2, col = (c & 3) * 8;
      gload_lds16(A + (((size_t)(tileM + row)) << 10) + k0 + col, &As[c * 8]);
      gload_lds16(Bw + (((size_t)(tileN + row)) << 10) + k0 + col, &Bs[c * 8]);
    }
    __syncthreads();
    s16x8 af[4], bf[4];
#pragma unroll
    for (int i = 0; i < 4; ++i)
      af[i] = *(const s16x8*)&As[(wr * 64 + i * 16 + l15) * 32 + l16 * 8];
#pragma unroll
    for (int i = 0; i < 4; ++i)
      bf[i] = *(const s16x8*)&Bs[(wc * 64 + i * 16 + l15) * 32 + l16 * 8];
#pragma unroll
    for (int i = 0; i < 4; ++i)
#pragma unroll
      for (int j = 0; j < 4; ++j)
        acc[i][j] = __builtin_amdgcn_mfma_f32_16x16x32_bf16(af[i], bf[j], acc[i][j], 0, 0, 0);
    __syncthreads();
  }
#pragma unroll
  for (int i = 0; i < 4; ++i) {
#pragma unroll
    for (int j = 0; j < 4; ++j) {
      int n = tileN + wc * 64 + j * 16 + l15;
      float bv = bias[n];
#pragma unroll
      for (int r = 0; r < 4; ++r) {
        int m = tileM + wr * 64 + i * 16 + l16 * 4 + r;
        float v = (acc[i][j][r] + bv) * scl;
        if (MODE == 0) {
          int b_ = m >> 11, s_ = m & 2047, h_ = n >> 6, d_ = n & 63;
          ((unsigned short*)Cout)[(((size_t)(b_ * H + h_) * S) + s_) * DK + d_] = f2bf(v);
        } else {
          ((float*)Cout)[(size_t)m * 1024 + n] = v;
        }
      }
    }
  }
}

__global__ __launch_bounds__(256) void k_gemm_qkv(
    const unsigned short* __restrict__ Xq, const unsigned short* __restrict__ Xk,
    const unsigned short* __restrict__ Xv,
    const unsigned short* __restrict__ Wq, const unsigned short* __restrict__ Wk,
    const unsigned short* __restrict__ Wv,
    const float* __restrict__ bq, const float* __restrict__ bk, const float* __restrict__ bv,
    unsigned short* __restrict__ oq, unsigned short* __restrict__ ok, unsigned short* __restrict__ ov) {
  __shared__ alignas(16) unsigned short As[128 * 32];
  __shared__ alignas(16) unsigned short Bs[128 * 32];
  int flat = (blockIdx.z * 32 + blockIdx.y) * 8 + blockIdx.x;   // [0,768)
  int swz = (flat & 7) * 96 + (flat >> 3);                      // bijective (768 = 8*96)
  int z = swz >> 8;
  int rem = swz & 255;
  int ty = rem >> 3, tx = rem & 7;
  const unsigned short* A = z == 0 ? Xq : z == 1 ? Xk : Xv;
  const unsigned short* W = z == 0 ? Wq : z == 1 ? Wk : Wv;
  const float* bias = z == 0 ? bq : z == 1 ? bk : bv;
  unsigned short* o = z == 0 ? oq : z == 1 ? ok : ov;
  float scl = z == 0 ? 0.125f : 1.0f;
  gemm_tile<0>(A, W, bias, o, ty * 128, tx * 128, scl, As, Bs);
}

__global__ __launch_bounds__(256) void k_gemm_out(const unsigned short* __restrict__ A,
                                                  const unsigned short* __restrict__ W,
                                                  const float* __restrict__ bias,
                                                  float* __restrict__ Cout) {
  __shared__ alignas(16) unsigned short As[128 * 32];
  __shared__ alignas(16) unsigned short Bs[128 * 32];
  int flat = blockIdx.y * 8 + blockIdx.x;                        // [0,256)
  int swz = (flat & 7) * 32 + (flat >> 3);                       // bijective (256 = 8*32)
  int ty = swz >> 3, tx = swz & 7;
  gemm_tile<1>(A, W, bias, Cout, ty * 128, tx * 128, 1.0f, As, Bs);
}

// ------- V transpose: [bh][s][64] -> tile-blocked vt2[bh][kt][64 d][64 s] -------
__global__ __launch_bounds__(256) void k_transpose_v(const unsigned short* __restrict__ vstd,
                                                     unsigned short* __restrict__ vt2) {
  __shared__ alignas(16) unsigned short T[64][72];
  int bh = blockIdx.y, st = blockIdx.x;
  int t = threadIdx.x;
  int rr = t >> 3, cc = (t & 7) * 8;
#pragma unroll
  for (int i = 0; i < 2; ++i) {
    int r = rr + i * 32;
    u16x8 v = *(const u16x8*)&vstd[((size_t)bh * S + st * 64 + r) * 64 + cc];
    *(u16x8*)&T[r][cc] = v;
  }
  __syncthreads();
#pragma unroll
  for (int i = 0; i < 2; ++i) {
    int d = rr + i * 32;
    u16x8 o;
#pragma unroll
    for (int j = 0; j < 8; ++j) o[j] = T[cc + j][d];
    *(u16x8*)&vt2[(size_t)bh * S * 64 + st * 4096 + d * 64 + cc] = o;
  }
}

// ============ fused attention: O-pass + weights-write in ONE kernel ============
// grid 2048 (64 qtiles x 32 bh), 4 waves, block = 32 q-rows.
// Pass 1: swapped QK^T (lane owns one q: per-lane lsum, no shuffles); P packed
//   in-register via cvt_pk+permlane32_swap (round-5-verified); PV from LDS-staged
//   K[128x64]/V^T[64x128] tiles (single-buffered, 2 barriers/tile; >=4 blocks/CU
//   gives implicit overlap). O combined cross-wave via LDS, normalized, stored.
// Pass 2: unswapped QK^T (Q frags are register-identical between A/B roles),
//   w = exp2(s*log2e - nl2l), coalesced nontemporal stores (the 537MB write).
// Pass-1 compute of some blocks hides under pass-2 write stalls of others.
__global__ __launch_bounds__(256) void k_attn_fused(const unsigned short* __restrict__ qw,
                                                    const unsigned short* __restrict__ kw,
                                                    const unsigned short* __restrict__ vt2,
                                                    const int* __restrict__ mask,
                                                    unsigned short* __restrict__ aout,
                                                    float* __restrict__ attw) {
  __shared__ alignas(16) char lds[33536];
  unsigned short* Ks = (unsigned short*)lds;            // [128 key][64 dk], 128B rows, swz (row&7)<<4
  unsigned short* Vs = (unsigned short*)(lds + 16384);  // [64 d][128 key], 256B rows, swz (row&15)<<4
  float* lsumW = (float*)(lds + 32768);                 // [4 wave][32 q]
  float* lsumT = (float*)(lds + 33280);                 // [32 q] linear total
  float* nl2lW = (float*)(lds + 33408);                 // [32 q] log2(total)
  const float LOG2E = 1.44269504f;

  int flat = blockIdx.y * 64 + blockIdx.x;              // 2048 blocks
  int swzb = (flat & 7) * 256 + (flat >> 3);            // bijective XCD chunks
  const int bh = swzb >> 6, b = bh >> 4, h = bh & 15;
  const int q0 = (swzb & 63) * 32;
  const int tid = threadIdx.x;
  const int lane = tid & 63, w = tid >> 6;
  const int l31 = lane & 31, hi = lane >> 5;

  const unsigned short* kw_bh = kw + (size_t)bh * S * 64;
  const unsigned short* vt_bh = vt2 + (size_t)bh * S * 64;
  const int* mrow = mask + b * S;

  // Q fragments: lane=q(l31), k=dk chunk. Same registers serve pass-1 B-operand
  // and pass-2 A-operand (identical lane->element mapping).
  s16x8 qf[4];
  const unsigned short* qbase = qw + ((size_t)bh * S + q0 + l31) * 64 + hi * 8;
#pragma unroll
  for (int kc = 0; kc < 4; ++kc) qf[kc] = *(const s16x8*)(qbase + kc * 16);

  // ---------------- pass 1 ----------------
  f32x16 oT0 = {}, oT1 = {};
  float lsum = 0.f;
  const int swv = (l31 & 15) << 4;   // V-row swizzle (d&15 == l31&15 for both d-halves)

  for (int t = 0; t < 16; ++t) {
    // stage K tile: 128 rows x 64 dk (16KB), inverse-swizzled source
#pragma unroll
    for (int p = 0; p < 4; ++p) {
      int c = tid + p * 256, row = c >> 3, cc = (c & 7) ^ (row & 7);
      gload_lds16(kw_bh + ((size_t)(t * 128 + row)) * 64 + cc * 8, Ks + c * 8);
    }
    // stage V tile: 64 d x 128 key (16KB) from two vt2 kt-subtiles
#pragma unroll
    for (int p = 0; p < 4; ++p) {
      int c = tid + p * 256, row = c >> 4, c16 = (c & 15) ^ (row & 15);
      gload_lds16(vt_bh + (size_t)(t * 2 + (c16 >> 3)) * 4096 + row * 64 + (c16 & 7) * 8,
                  Vs + c * 8);
    }
    __syncthreads();

    // QK^T swapped: sT = K * Q -> col=lane=q, row=key
    const int krow = w * 32 + l31;
    f32x16 sT = {};
#pragma unroll
    for (int kc = 0; kc < 4; ++kc) {
      s16x8 ka = *(const s16x8*)((const char*)Ks + krow * 128 +
                                 ((kc * 32 + hi * 16) ^ ((krow & 7) << 4)));
      sT = __builtin_amdgcn_mfma_f32_32x32x16_bf16(ka, qf[kc], sT, 0, 0, 0);
    }

    // mask (key = base + (r&3)+8*(r>>2)+4*hi), grouped dwordx4 loads
    int base = t * 128 + w * 32 + 4 * hi;
    int m[16];
    *(int4*)&m[0]  = *(const int4*)&mrow[base];
    *(int4*)&m[4]  = *(const int4*)&mrow[base + 8];
    *(int4*)&m[8]  = *(const int4*)&mrow[base + 16];
    *(int4*)&m[12] = *(const int4*)&mrow[base + 24];

    float e[16];
#pragma unroll
    for (int r = 0; r < 16; ++r) {
      e[r] = m[r] ? exp2f(sT[r] * LOG2E) : 0.f;
      lsum += e[r];
    }

    // pack P to bf16 B-fragments in-register (round-5-verified)
    unsigned x0 = cvt_pk_bf16(e[0], e[1]),   x1 = cvt_pk_bf16(e[2], e[3]);
    unsigned x2 = cvt_pk_bf16(e[4], e[5]),   x3 = cvt_pk_bf16(e[6], e[7]);
    unsigned x4 = cvt_pk_bf16(e[8], e[9]),   x5 = cvt_pk_bf16(e[10], e[11]);
    unsigned x6 = cvt_pk_bf16(e[12], e[13]), x7 = cvt_pk_bf16(e[14], e[15]);
    perm32swap(x0, x2); perm32swap(x1, x3);
    perm32swap(x4, x6); perm32swap(x5, x7);
    union { unsigned u[4]; s16x8 v; } p0u, p1u;
    p0u.u[0] = x0; p0u.u[1] = x1; p0u.u[2] = x2; p0u.u[3] = x3;
    p1u.u[0] = x4; p1u.u[1] = x5; p1u.u[2] = x6; p1u.u[3] = x7;

    // PV: oT = V^T * P (A: lane=d, k=key chunk from LDS)
    const int ko0 = w * 64 + hi * 16, ko1 = w * 64 + 32 + hi * 16;
    const char* Vr0 = (const char*)Vs + l31 * 256;
    const char* Vr1 = (const char*)Vs + (32 + l31) * 256;
    s16x8 va;
    va = *(const s16x8*)(Vr0 + (ko0 ^ swv));
    oT0 = __builtin_amdgcn_mfma_f32_32x32x16_bf16(va, p0u.v, oT0, 0, 0, 0);
    va = *(const s16x8*)(Vr0 + (ko1 ^ swv));
    oT0 = __builtin_amdgcn_mfma_f32_32x32x16_bf16(va, p1u.v, oT0, 0, 0, 0);
    va = *(const s16x8*)(Vr1 + (ko0 ^ swv));
    oT1 = __builtin_amdgcn_mfma_f32_32x32x16_bf16(va, p0u.v, oT1, 0, 0, 0);
    va = *(const s16x8*)(Vr1 + (ko1 ^ swv));
    oT1 = __builtin_amdgcn_mfma_f32_32x32x16_bf16(va, p1u.v, oT1, 0, 0, 0);

    __syncthreads();   // all waves done reading tile before next stage
  }

  // ---- lsum combine + O partials to LDS (Ks/Vs region now free) ----
  lsum += __shfl_xor(lsum, 32);
  if (hi == 0) lsumW[w * 32 + l31] = lsum;

  // write O partials, swizzled rows of 256B: [w][q=l31][d]
  {
    char* orow = (char*)lds + w * 8192 + l31 * 256;
#pragma unroll
    for (int rg = 0; rg < 4; ++rg) {
      f32x4 c0, c1;
#pragma unroll
      for (int j = 0; j < 4; ++j) { c0[j] = oT0[rg * 4 + j]; c1[j] = oT1[rg * 4 + j]; }
      *(f32x4*)(orow + ((rg * 32 + hi * 16) ^ swv)) = c0;          // d = 8*rg+4*hi
      *(f32x4*)(orow + ((128 + rg * 32 + hi * 16) ^ swv)) = c1;    // d += 32
    }
  }
  __syncthreads();

  if (tid < 32) {
    float tot = lsumW[tid] + lsumW[32 + tid] + lsumW[64 + tid] + lsumW[96 + tid];
    lsumT[tid] = tot;
    nl2lW[tid] = __log2f(tot);
  }
  __syncthreads();

  // ---- O: sum 4 wave-partials, normalize, coalesced store ----
  {
    int q = tid >> 3, dg = tid & 7;
    float inv = 1.f / lsumT[q];
    int sq = (q & 15) << 4;
    float s[8] = {};
#pragma unroll
    for (int w4 = 0; w4 < 4; ++w4) {
      const char* prow = (const char*)lds + w4 * 8192 + q * 256;
      f32x4 a = *(const f32x4*)(prow + ((dg * 32) ^ sq));
      f32x4 bb = *(const f32x4*)(prow + ((dg * 32 + 16) ^ sq));
#pragma unroll
      for (int j = 0; j < 4; ++j) { s[j] += a[j]; s[4 + j] += bb[j]; }
    }
    u16x8 ob;
#pragma unroll
    for (int j = 0; j < 8; ++j) ob[j] = f2bf(s[j] * inv);
    *(u16x8*)&aout[((size_t)b * S + q0 + q) * D + h * 64 + dg * 8] = ob;
  }

  // ---------------- pass 2: weights write (k_weights verbatim) ----------------
  float nl2l[16];
#pragma unroll
  for (int r = 0; r < 16; ++r) nl2l[r] = nl2lW[(r & 3) + 8 * (r >> 2) + 4 * hi];

  for (int it = 0; it < 16; ++it) {
    int key0 = it * 128 + w * 32;
    const unsigned short* kbase = kw_bh + (size_t)(key0 + l31) * 64 + hi * 8;
    s16x8 kb[4];
#pragma unroll
    for (int kc = 0; kc < 4; ++kc) kb[kc] = *(const s16x8*)(kbase + kc * 16);
    f32x16 dacc = {};
#pragma unroll
    for (int kc = 0; kc < 4; ++kc)
      dacc = __builtin_amdgcn_mfma_f32_32x32x16_bf16(qf[kc], kb[kc], dacc, 0, 0, 0);

    int key = key0 + l31;
    int mk = mrow[key];
    float* obase = attw + ((size_t)bh * S + q0) * S + key;
#pragma unroll
    for (int r = 0; r < 16; ++r) {
      int row = (r & 3) + 8 * (r >> 2) + 4 * hi;
      float wv = mk ? exp2f(dacc[r] * LOG2E - nl2l[r]) : 0.f;
      __builtin_nontemporal_store(wv, obase + (size_t)row * S);
    }
  }
}

// ---------------- host ----------------
extern "C" void kernel_launch(void* const* d_in, const int* in_sizes, int n_in,
                              void* d_out, int out_size, void* d_ws, size_t ws_size,
                              hipStream_t stream) {
  (void)in_sizes; (void)n_in; (void)out_size; (void)ws_size;
  const float* Q  = (const float*)d_in[0];
  const float* K  = (const float*)d_in[1];
  const float* V  = (const float*)d_in[2];
  const int* mask = (const int*)d_in[3];
  const float* Wq = (const float*)d_in[4];
  const float* bq = (const float*)d_in[5];
  const float* Wk = (const float*)d_in[6];
  const float* bk = (const float*)d_in[7];
  const float* Wv = (const float*)d_in[8];
  const float* bv = (const float*)d_in[9];
  const float* Wo = (const float*)d_in[10];
  const float* bo = (const float*)d_in[11];

  char* ws = (char*)d_ws;
  unsigned short* Xbf  = (unsigned short*)(ws + 0);           // [3][4194304] bf16
  unsigned short* Wbf  = (unsigned short*)(ws + 25165824);    // [4][1048576] bf16
  unsigned short* qws  = (unsigned short*)(ws + 33554432);    // [bh][s][64]
  unsigned short* kws  = (unsigned short*)(ws + 41943040);    // [bh][s][64]
  unsigned short* vstd = (unsigned short*)(ws + 50331648);    // [bh][s][64]
  unsigned short* vt2  = (unsigned short*)(ws + 0);           // reuse Xbf[Q] (consumed)
  unsigned short* aoutb= (unsigned short*)(ws + 8388608);     // reuse Xbf[K] (consumed)
  float* out0 = (float*)d_out;
  float* attw = (float*)d_out + OUT0;

  k_cvt3<<<dim3(2048, 3), dim3(256), 0, stream>>>(Q, K, V, Xbf, Xbf + 4194304, Xbf + 8388608);
  k_cvt4<<<dim3(512, 4), dim3(256), 0, stream>>>(Wq, Wk, Wv, Wo,
                                                 Wbf, Wbf + 1048576, Wbf + 2097152, Wbf + 3145728);

  k_gemm_qkv<<<dim3(8, 32, 3), dim3(256), 0, stream>>>(
      Xbf, Xbf + 4194304, Xbf + 8388608,
      Wbf, Wbf + 1048576, Wbf + 2097152,
      bq, bk, bv, qws, kws, vstd);

  k_transpose_v<<<dim3(32, 32), dim3(256), 0, stream>>>(vstd, vt2);

  k_attn_fused<<<dim3(64, 32), dim3(256), 0, stream>>>(qws, kws, vt2, mask, aoutb, attw);

  k_gemm_out<<<dim3(8, 32), dim3(256), 0, stream>>>(aoutb, Wbf + 3145728, bo, out0);
}